// Round 7
// baseline (171.078 us; speedup 1.0000x reference)
//
#include <hip/hip_runtime.h>
#include <stdint.h>

// B=8, OBJ=128, INP=64, HID=256, D=192.
// R28: j-split pair for 3 waves/SIMD WITHOUT touching launch_bounds.
// Lesson from R22-R24: tightening launch_bounds makes the allocator spill;
// R0/R27 show (256,2) allocates exactly natural demand. So lower the
// NATURAL demand below 170 (3-wave threshold at 512 regs/SIMD): each block
// handles one (row, j-half): hbuf 64x256=32KB, acc[2][2]=64 AGPR,
// bfr[2][2]=16, af ring-4 32 -> ~150 total. Blocks are barrier-independent
// -> 3 staggered waves/SIMD hide each other's drains. j-halves combine via
// atomicAdd into msg (zeroed by setup each iteration; same-stream order).
// Cost: wt L2 traffic x2 (512MB agg ~ absorbed). Decoder = R27 v2.
// Failure rule: VGPR>=110 or pair>=55us -> abandon, try coop merge.

#define HID 256
#define NOBJ 128
#define NROW 1024   // B*OBJ

typedef __attribute__((ext_vector_type(8))) short short8;
typedef __attribute__((ext_vector_type(4))) float float4v;
typedef __attribute__((ext_vector_type(16))) float float16v;
typedef __attribute__((ext_vector_type(2))) unsigned int uint2v;

__device__ __forceinline__ unsigned int f2bf_u(float f) {
    unsigned int u = __builtin_bit_cast(unsigned int, f);
    u += 0x7fffu + ((u >> 16) & 1u);   // RNE
    return u >> 16;
}
__device__ __forceinline__ unsigned int pack2(float a, float b) {
    return f2bf_u(a) | (f2bf_u(b) << 16);
}
__device__ __forceinline__ float relu(float v) { return v > 0.f ? v : 0.f; }

// LDS-only barrier: leaves global-load (vmcnt) prefetches in flight.
__device__ __forceinline__ void lds_barrier() {
    asm volatile("s_waitcnt lgkmcnt(0)\n\ts_barrier" ::: "memory");
}

// ---- setup:
//  blocks [0,16): fragment-major pack of w1,w2 (layer m = bx>>3, n-tile tau = bx&7)
//  blocks [16,528): encoder, 2 rows each (fold b_enc into ea) + zero msg rows
//  blocks [528,784): W34 row m = bx-528:  W34[m][o] = sum_k w3[m][k]*wd1[k][o]
//  block  784:       b34[o] = sum_k b3[k]*wd1[k][o] + bd1[o]
__global__ void setup_kernel(const float* __restrict__ x0, const float* __restrict__ x1,
                             const float* __restrict__ x2, const float* __restrict__ w_enc,
                             const float* __restrict__ b_enc,
                             const float* __restrict__ w1, const float* __restrict__ w2,
                             const float* __restrict__ w3, const float* __restrict__ b3,
                             const float* __restrict__ wd1, const float* __restrict__ bd1,
                             unsigned short* __restrict__ wt,
                             float* __restrict__ ea, float* __restrict__ eb,
                             float* __restrict__ W34, float* __restrict__ b34,
                             float* __restrict__ msg) {
    const int bx = blockIdx.x, t = threadIdx.x;
    __shared__ float lw[256][33];          // [k][n-within-tile]
    __shared__ float xs[2][192];
    if (bx < 16) {
        const int m = bx >> 3, tau = bx & 7;
        const float* w = (m == 0) ? w1 : w2;
        const int n = t & 31, kk = t >> 5;     // 8 k-rows per pass
#pragma unroll
        for (int rep = 0; rep < 32; ++rep) {
            int k = rep * 8 + kk;
            lw[k][n] = w[k * 256 + tau * 32 + n];   // coalesced 128B segments
        }
        __syncthreads();
        unsigned short* outp = wt + (m * 8 + tau) * 8192;
        const int lane = t & 63, wq = t >> 6;
        const int h5 = lane >> 5, l31n = lane & 31;
#pragma unroll
        for (int rep = 0; rep < 4; ++rep) {
            const int kb = wq * 4 + rep;
            short8 v;
#pragma unroll
            for (int e = 0; e < 8; ++e)
                v[e] = (short)f2bf_u(lw[kb * 16 + h5 * 8 + e][l31n]);
            *(short8*)(outp + kb * 512 + lane * 8) = v;   // wave-contiguous 1KB
        }
        return;
    }
    if (bx < 528) {
        const int e = bx - 16;                 // 512 groups x 2 rows
        // zero the msg rows this group owns (pair accumulates atomically)
        msg[e * 512 + t] = 0.f;
        msg[e * 512 + 256 + t] = 0.f;
        for (int idx = t; idx < 384; idx += 256) {
            int r = idx / 192, d = idx % 192;
            int row = e * 2 + r;
            float v = (d < 64) ? x0[row * 64 + d]
                    : (d < 128) ? x1[row * 64 + d - 64]
                    : x2[row * 64 + d - 128];
            xs[r][d] = v;
        }
        __syncthreads();
        float aA[2] = {0.f, 0.f}, aB[2] = {0.f, 0.f};
#pragma unroll 16
        for (int d = 0; d < 192; ++d) {
            float wa = w_enc[d * 256 + t];
            float wb = w_enc[(192 + d) * 256 + t];
#pragma unroll
            for (int r = 0; r < 2; ++r) { aA[r] += xs[r][d] * wa; aB[r] += xs[r][d] * wb; }
        }
        float be = b_enc[t];
#pragma unroll
        for (int r = 0; r < 2; ++r) {
            ea[(e * 2 + r) * 256 + t] = aA[r] + be;
            eb[(e * 2 + r) * 256 + t] = aB[r];
        }
        return;
    }
    if (bx < 784) {
        const int m = bx - 528;
        float a = 0.f;
#pragma unroll 8
        for (int k = 0; k < 256; ++k) a += w3[m * 256 + k] * wd1[k * 256 + t];
        W34[m * 256 + t] = a;
        return;
    }
    {   // b34
        float a = bd1[t];
#pragma unroll 8
        for (int k = 0; k < 256; ++k) a += b3[k] * wd1[k * 256 + t];
        b34[t] = a;
    }
}

// ---- pair MLP (2 layers) + pool partial: grid 2048, one WG per (row, j-half).
//      w = bx>>1, jh = bx&1; 64 j-rows in 32KB LDS. swizzle: elem(j,k) at
//      j*256 + ((k>>3 ^ (j&31))<<3) + (k&7). Wave wv owns n-quarter n0=wv*64
//      as tn=2 x tj=2 tiles of 32x32x16. af ring-4. Pool partial is
//      atomicAdd'ed into msg (setup zeroed it).
__global__ __launch_bounds__(256, 2) void pair_kernel(
        const float* __restrict__ ea, const float* __restrict__ eb,
        const unsigned short* __restrict__ wt,
        const float* __restrict__ b1, const float* __restrict__ b2,
        float* __restrict__ msg) {
    __shared__ __align__(16) unsigned short hbuf[64 * 256];   // 32 KB

    const int bx = blockIdx.x;
    const int w = bx >> 1, jh = bx & 1, b = w >> 7;
    const int t = threadIdx.x, wv = t >> 6, lane = t & 63;
    const int l31 = lane & 31, h5 = lane >> 5;
    const int n0 = wv * 64;

    const unsigned short* aptr = wt + lane * 8;   // + ((l*8 + wv*2+tn)*16 + kb)*512

    short8 af[4][2], bfr[2][2];
    // ring-4 preload: steps g = 0,1,2 of layer 0
#pragma unroll
    for (int pg = 0; pg < 3; ++pg) {
        af[pg][0] = *(const short8*)(aptr + ((wv * 2 + 0) * 16 + pg) * 512);
        af[pg][1] = *(const short8*)(aptr + ((wv * 2 + 1) * 16 + pg) * 512);
    }

    // preamble: h0[j][k] = relu(ea[w][k] + eb[b*128 + jh*64 + j][k]);
    // wave fills j = wv*16 .. wv*16+15 (j local to this half)
    {
        const float4v va = *(const float4v*)(ea + w * 256 + lane * 4);
        const float* ebbase = eb + (b * NOBJ + jh * 64) * 256;
        const int c = lane >> 1, sub = (lane & 1) * 4;
#pragma unroll 4
        for (int jj = 0; jj < 16; ++jj) {
            const int j = wv * 16 + jj;
            float4v vb = *(const float4v*)(ebbase + j * 256 + lane * 4);
            int addr = j * 256 + ((c ^ (j & 31)) << 3) + sub;
            *(uint2v*)(hbuf + addr) = (uint2v){
                pack2(relu(va[0] + vb[0]), relu(va[1] + vb[1])),
                pack2(relu(va[2] + vb[2]), relu(va[3] + vb[3]))};
        }
    }
    lds_barrier();

    int jb[2];
#pragma unroll
    for (int tj = 0; tj < 2; ++tj) jb[tj] = (tj * 32 + l31) * 256;
#pragma unroll
    for (int tj = 0; tj < 2; ++tj)
        bfr[0][tj] = *(const short8*)(hbuf + jb[tj] + ((h5 ^ l31) << 3));

    float16v acc[2][2];   // [tn][tj]

#pragma unroll
    for (int l = 0; l < 2; ++l) {
        const float* bias = (l == 0) ? b1 : b2;
#pragma unroll
        for (int tn = 0; tn < 2; ++tn)
#pragma unroll
            for (int q = 0; q < 4; ++q) {
                float4v bv = *(const float4v*)(bias + n0 + tn * 32 + q * 8 + h5 * 4);
#pragma unroll
                for (int i = 0; i < 4; ++i)
#pragma unroll
                    for (int tj = 0; tj < 2; ++tj)
                        acc[tn][tj][q * 4 + i] = bv[i];
            }
#pragma unroll
        for (int kb = 0; kb < 16; ++kb) {
            const int g = l * 16 + kb, gp = g + 3;
            if (gp < 32) {   // ring-4: prefetch 3 steps ahead (crosses layers)
                const int lp = gp >> 4, kp = gp & 15;
                af[gp & 3][0] = *(const short8*)(aptr + ((lp * 8 + wv * 2 + 0) * 16 + kp) * 512);
                af[gp & 3][1] = *(const short8*)(aptr + ((lp * 8 + wv * 2 + 1) * 16 + kp) * 512);
            }
            if (kb < 15) {   // prefetch next step's B from LDS
                const int off = ((((kb + 1) * 2 + h5) ^ l31) << 3);
#pragma unroll
                for (int tj = 0; tj < 2; ++tj)
                    bfr[(kb + 1) & 1][tj] = *(const short8*)(hbuf + jb[tj] + off);
            }
#pragma unroll
            for (int tn = 0; tn < 2; ++tn)
#pragma unroll
                for (int tj = 0; tj < 2; ++tj)
                    acc[tn][tj] = __builtin_amdgcn_mfma_f32_32x32x16_bf16(
                        af[g & 3][tn], bfr[kb & 1][tj], acc[tn][tj], 0, 0, 0);
        }

        if (l == 0) {
            lds_barrier();   // hbuf reads of layer 0 done
            // writeback h1 (relu, bf16) into swizzled layout
#pragma unroll
            for (int tn = 0; tn < 2; ++tn)
#pragma unroll
                for (int q = 0; q < 4; ++q) {
                    const int nb_ = n0 + tn * 32 + 8 * q + 4 * h5;
                    const int cn = nb_ >> 3, sub = nb_ & 7;
#pragma unroll
                    for (int tj = 0; tj < 2; ++tj) {
                        const int j = tj * 32 + l31;
                        int addr = j * 256 + ((cn ^ l31) << 3) + sub;
                        *(uint2v*)(hbuf + addr) = (uint2v){
                            pack2(relu(acc[tn][tj][q * 4]), relu(acc[tn][tj][q * 4 + 1])),
                            pack2(relu(acc[tn][tj][q * 4 + 2]), relu(acc[tn][tj][q * 4 + 3]))};
                    }
                }
            lds_barrier();
#pragma unroll
            for (int tj = 0; tj < 2; ++tj)
                bfr[0][tj] = *(const short8*)(hbuf + jb[tj] + ((h5 ^ l31) << 3));
        }
    }

    // ---- pool partial over this half's 64 j rows; accumulate into msg.
    // col j = l31, row n = n0 + tn*32 + (r&3) + 8*(r>>2) + 4*h5
#pragma unroll
    for (int tn = 0; tn < 2; ++tn)
#pragma unroll
        for (int r = 0; r < 16; ++r) {
            float s = relu(acc[tn][0][r]) + relu(acc[tn][1][r]);
            s += __shfl_xor(s, 1);
            s += __shfl_xor(s, 2);
            s += __shfl_xor(s, 4);
            s += __shfl_xor(s, 8);
            s += __shfl_xor(s, 16);
            if (l31 == 0) {
                const int n = n0 + tn * 32 + (r & 3) + 8 * (r >> 2) + 4 * h5;
                atomicAdd(&msg[w * 256 + n], s * 0.0078125f);   // /128
            }
        }
}

// ---- decoder v2 (unchanged from R27): out = relu(m2@W34 + b34) @ wd2 + bd2.
//      grid 256 (every CU), 512 threads (2 waves/SIMD), 4 rows/block,
//      2-way k-split both stages, unroll 16 -> deep load pipeline.
__global__ __launch_bounds__(512) void decoder_kernel(
        const float* __restrict__ msg, const float* __restrict__ W34,
        const float* __restrict__ b34, const float* __restrict__ wd2,
        const float* __restrict__ bd2, float* __restrict__ out) {
    __shared__ float ml[4][256];        // m2 rows
    __shared__ float ps[2][4][256];     // stage1 partials [kh][r][n]
    __shared__ float tl[4][256];        // t1 rows
    __shared__ float p2[2][4][64];      // stage2 partials [kh][r][o]
    const int bx = blockIdx.x, t = threadIdx.x;
    const int r0 = bx * 4;

#pragma unroll
    for (int i = t; i < 1024; i += 512) ml[i >> 8][i & 255] = msg[r0 * 256 + i];
    __syncthreads();

    // stage 1: ps[kh][r][n] = sum_{k in kh-half} m2[r][k] * W34[k][n]
    {
        const int n = t & 255, kh = t >> 8;
        float a0 = 0.f, a1 = 0.f, a2 = 0.f, a3 = 0.f;
        const float* wp = W34 + (kh * 128) * 256 + n;
        const float* m0 = &ml[0][kh * 128];
        const float* m1 = &ml[1][kh * 128];
        const float* m2r = &ml[2][kh * 128];
        const float* m3 = &ml[3][kh * 128];
#pragma unroll 16
        for (int k = 0; k < 128; ++k) {
            const float wv_ = wp[k * 256];
            a0 += m0[k] * wv_;
            a1 += m1[k] * wv_;
            a2 += m2r[k] * wv_;
            a3 += m3[k] * wv_;
        }
        ps[kh][0][n] = a0; ps[kh][1][n] = a1; ps[kh][2][n] = a2; ps[kh][3][n] = a3;
    }
    __syncthreads();
#pragma unroll
    for (int i = t; i < 1024; i += 512) {
        const int r = i >> 8, nn = i & 255;
        tl[r][nn] = relu(ps[0][r][nn] + ps[1][r][nn] + b34[nn]);
    }
    __syncthreads();

    // stage 2: p2[kh][r][o] = sum_{k in kh-half} t1[r][k] * wd2[k][o]
    {
        const int o = t & 63, rr = (t >> 6) & 3, kh = t >> 8;
        float a = 0.f;
        const float* w2p = wd2 + (kh * 128) * 64 + o;
        const float* tp = &tl[rr][kh * 128];
#pragma unroll 16
        for (int k = 0; k < 128; ++k) a += tp[k] * w2p[k * 64];
        p2[kh][rr][o] = a;
    }
    __syncthreads();
    if (t < 256) {
        const int o = t & 63, r = t >> 6;
        out[(r0 + r) * 64 + o] = p2[0][r][o] + p2[1][r][o] + bd2[o];
    }
}

extern "C" void kernel_launch(void* const* d_in, const int* in_sizes, int n_in,
                              void* d_out, int out_size, void* d_ws, size_t ws_size,
                              hipStream_t stream) {
    const float* x0    = (const float*)d_in[0];
    const float* x1    = (const float*)d_in[1];
    const float* x2    = (const float*)d_in[2];
    const float* w_enc = (const float*)d_in[3];
    const float* b_enc = (const float*)d_in[4];
    const float* w1    = (const float*)d_in[5];
    const float* b1    = (const float*)d_in[6];
    const float* w2    = (const float*)d_in[7];
    const float* b2    = (const float*)d_in[8];
    const float* w3    = (const float*)d_in[9];
    const float* b3    = (const float*)d_in[10];
    const float* wd1   = (const float*)d_in[11];
    const float* bd1   = (const float*)d_in[12];
    const float* wd2   = (const float*)d_in[13];
    const float* bd2   = (const float*)d_in[14];
    float* out = (float*)d_out;

    // workspace: wfrag 256KB (384KB slot) | ea 1MB | eb 1MB | W34 256KB |
    //            b34 1KB | msg 1MB
    unsigned short* wt = (unsigned short*)d_ws;
    float* ea  = (float*)((char*)d_ws + 3 * 65536 * sizeof(unsigned short));
    float* eb  = ea + NROW * HID;
    float* W34 = eb + NROW * HID;
    float* b34 = W34 + 256 * 256;
    float* msg = b34 + 256;

    setup_kernel<<<785, 256, 0, stream>>>(x0, x1, x2, w_enc, b_enc, w1, w2,
                                          w3, b3, wd1, bd1, wt, ea, eb, W34, b34, msg);
    pair_kernel<<<2 * NROW, 256, 0, stream>>>(ea, eb, wt, b1, b2, msg);
    decoder_kernel<<<NROW / 4, 512, 0, stream>>>(msg, W34, b34, wd2, bd2, out);
}

// Round 8
// 147.233 us; speedup vs baseline: 1.1620x; 1.1620x over previous
//
#include <hip/hip_runtime.h>
#include <stdint.h>

// B=8, OBJ=128, INP=64, HID=256, D=192.
// R29: 8-wave blocks, full j=128, register-exact occupancy. Lessons:
// R22-R24: tight launch_bounds + big AGPR acc -> allocator pins arch at a
// 64-granule and spills the excess. R28: j-split halves per-block MFMA but
// not per-block fixed cost -> slower despite 34% occupancy. R27: occupancy
// is LDS-bound (64KB -> 2 blk/CU). Fix: ONE 512-thread block per row,
// 8 waves, wave owns 32-wide n-slice (tn=1, tj=4): acc = 64 AGPR, arch
// demand ~52 (af ring-4 16 + bfr SINGLE-buffer 16 + misc) fits the 64-arch
// granule at launch_bounds(512,4) -> 2 blocks/CU = 4 waves/SIMD = 50% occ,
// per-CU MFMA work unchanged, per-wave phases halve. bfr prefetch dropped:
// 4-wave TLP hides the ~120cyc LDS stall (ILP->TLP trade).
// Binary check: WRITE_SIZE ~1MB = clean; >5MB = spill -> revert to R27.
// setup/decoder byte-identical to R27.

#define HID 256
#define NOBJ 128
#define NROW 1024   // B*OBJ

typedef __attribute__((ext_vector_type(8))) short short8;
typedef __attribute__((ext_vector_type(4))) float float4v;
typedef __attribute__((ext_vector_type(16))) float float16v;
typedef __attribute__((ext_vector_type(2))) unsigned int uint2v;

__device__ __forceinline__ unsigned int f2bf_u(float f) {
    unsigned int u = __builtin_bit_cast(unsigned int, f);
    u += 0x7fffu + ((u >> 16) & 1u);   // RNE
    return u >> 16;
}
__device__ __forceinline__ unsigned int pack2(float a, float b) {
    return f2bf_u(a) | (f2bf_u(b) << 16);
}
__device__ __forceinline__ float relu(float v) { return v > 0.f ? v : 0.f; }

// LDS-only barrier: leaves global-load (vmcnt) prefetches in flight.
__device__ __forceinline__ void lds_barrier() {
    asm volatile("s_waitcnt lgkmcnt(0)\n\ts_barrier" ::: "memory");
}

// ---- setup (byte-identical to R27):
//  blocks [0,16): fragment-major pack of w1,w2 (layer m = bx>>3, n-tile tau = bx&7)
//  blocks [16,528): encoder, 2 rows each (fold b_enc into ea)
//  blocks [528,784): W34 row m = bx-528:  W34[m][o] = sum_k w3[m][k]*wd1[k][o]
//  block  784:       b34[o] = sum_k b3[k]*wd1[k][o] + bd1[o]
__global__ void setup_kernel(const float* __restrict__ x0, const float* __restrict__ x1,
                             const float* __restrict__ x2, const float* __restrict__ w_enc,
                             const float* __restrict__ b_enc,
                             const float* __restrict__ w1, const float* __restrict__ w2,
                             const float* __restrict__ w3, const float* __restrict__ b3,
                             const float* __restrict__ wd1, const float* __restrict__ bd1,
                             unsigned short* __restrict__ wt,
                             float* __restrict__ ea, float* __restrict__ eb,
                             float* __restrict__ W34, float* __restrict__ b34) {
    const int bx = blockIdx.x, t = threadIdx.x;
    __shared__ float lw[256][33];          // [k][n-within-tile]
    __shared__ float xs[2][192];
    if (bx < 16) {
        const int m = bx >> 3, tau = bx & 7;
        const float* w = (m == 0) ? w1 : w2;
        const int n = t & 31, kk = t >> 5;     // 8 k-rows per pass
#pragma unroll
        for (int rep = 0; rep < 32; ++rep) {
            int k = rep * 8 + kk;
            lw[k][n] = w[k * 256 + tau * 32 + n];   // coalesced 128B segments
        }
        __syncthreads();
        unsigned short* outp = wt + (m * 8 + tau) * 8192;
        const int lane = t & 63, wq = t >> 6;
        const int h5 = lane >> 5, l31n = lane & 31;
#pragma unroll
        for (int rep = 0; rep < 4; ++rep) {
            const int kb = wq * 4 + rep;
            short8 v;
#pragma unroll
            for (int e = 0; e < 8; ++e)
                v[e] = (short)f2bf_u(lw[kb * 16 + h5 * 8 + e][l31n]);
            *(short8*)(outp + kb * 512 + lane * 8) = v;   // wave-contiguous 1KB
        }
        return;
    }
    if (bx < 528) {
        const int e = bx - 16;                 // 512 groups x 2 rows
        for (int idx = t; idx < 384; idx += 256) {
            int r = idx / 192, d = idx % 192;
            int row = e * 2 + r;
            float v = (d < 64) ? x0[row * 64 + d]
                    : (d < 128) ? x1[row * 64 + d - 64]
                    : x2[row * 64 + d - 128];
            xs[r][d] = v;
        }
        __syncthreads();
        float aA[2] = {0.f, 0.f}, aB[2] = {0.f, 0.f};
#pragma unroll 16
        for (int d = 0; d < 192; ++d) {
            float wa = w_enc[d * 256 + t];
            float wb = w_enc[(192 + d) * 256 + t];
#pragma unroll
            for (int r = 0; r < 2; ++r) { aA[r] += xs[r][d] * wa; aB[r] += xs[r][d] * wb; }
        }
        float be = b_enc[t];
#pragma unroll
        for (int r = 0; r < 2; ++r) {
            ea[(e * 2 + r) * 256 + t] = aA[r] + be;
            eb[(e * 2 + r) * 256 + t] = aB[r];
        }
        return;
    }
    if (bx < 784) {
        const int m = bx - 528;
        float a = 0.f;
#pragma unroll 8
        for (int k = 0; k < 256; ++k) a += w3[m * 256 + k] * wd1[k * 256 + t];
        W34[m * 256 + t] = a;
        return;
    }
    {   // b34
        float a = bd1[t];
#pragma unroll 8
        for (int k = 0; k < 256; ++k) a += b3[k] * wd1[k * 256 + t];
        b34[t] = a;
    }
}

// ---- pair MLP (2 layers) + pool: grid 1024, one WG (512 thr, 8 waves) per
//      (b,i). Full 128 j-rows in 64KB LDS; swizzle: elem(j,k) at
//      j*256 + ((k>>3 ^ (j&31))<<3) + (k&7). Wave wv owns n-slice n0=wv*32
//      as tj=4 tiles of 32x32x16 (4 MFMA/k-step). af ring-4, bfr single-buf.
__global__ __launch_bounds__(512, 4) void pair_kernel(
        const float* __restrict__ ea, const float* __restrict__ eb,
        const unsigned short* __restrict__ wt,
        const float* __restrict__ b1, const float* __restrict__ b2,
        float* __restrict__ msg) {
    __shared__ __align__(16) unsigned short hbuf[128 * 256];   // 64 KB
    __shared__ float ms[HID];

    const int w = blockIdx.x, b = w >> 7;
    const int t = threadIdx.x, wv = t >> 6, lane = t & 63;
    const int l31 = lane & 31, h5 = lane >> 5;
    const int n0 = wv * 32;

    const unsigned short* aptr = wt + lane * 8;   // + ((l*8 + wv)*16 + kb)*512

    short8 af[4], bfr[4];
    // ring-4 preload: steps g = 0,1,2 of layer 0
#pragma unroll
    for (int pg = 0; pg < 3; ++pg)
        af[pg] = *(const short8*)(aptr + (wv * 16 + pg) * 512);

    // preamble: h0[j][k] = relu(ea[w][k] + eb[b*128+j][k]); wave fills 16 rows
    {
        const float4v va = *(const float4v*)(ea + w * 256 + lane * 4);
        const float* ebbase = eb + (b * NOBJ) * 256;
        const int c = lane >> 1, sub = (lane & 1) * 4;
#pragma unroll 4
        for (int jj = 0; jj < 16; ++jj) {
            const int j = wv * 16 + jj;
            float4v vb = *(const float4v*)(ebbase + j * 256 + lane * 4);
            int addr = j * 256 + ((c ^ (j & 31)) << 3) + sub;
            *(uint2v*)(hbuf + addr) = (uint2v){
                pack2(relu(va[0] + vb[0]), relu(va[1] + vb[1])),
                pack2(relu(va[2] + vb[2]), relu(va[3] + vb[3]))};
        }
    }
    lds_barrier();

    int jb[4];
#pragma unroll
    for (int tj = 0; tj < 4; ++tj) jb[tj] = (tj * 32 + l31) * 256;

    float16v acc[4];   // [tj]

#pragma unroll
    for (int l = 0; l < 2; ++l) {
        const float* bias = (l == 0) ? b1 : b2;
#pragma unroll
        for (int q = 0; q < 4; ++q) {
            float4v bv = *(const float4v*)(bias + n0 + q * 8 + h5 * 4);
#pragma unroll
            for (int i = 0; i < 4; ++i)
#pragma unroll
                for (int tj = 0; tj < 4; ++tj)
                    acc[tj][q * 4 + i] = bv[i];
        }
#pragma unroll
        for (int kb = 0; kb < 16; ++kb) {
            const int g = l * 16 + kb, gp = g + 3;
            if (gp < 32) {   // ring-4: prefetch 3 steps ahead (crosses layers)
                const int lp = gp >> 4, kp = gp & 15;
                af[gp & 3] = *(const short8*)(aptr + ((lp * 8 + wv) * 16 + kp) * 512);
            }
            // single-buffered bfr: load this step's B, rely on TLP for latency
            {
                const int off = (((kb * 2 + h5) ^ l31) << 3);
#pragma unroll
                for (int tj = 0; tj < 4; ++tj)
                    bfr[tj] = *(const short8*)(hbuf + jb[tj] + off);
            }
#pragma unroll
            for (int tj = 0; tj < 4; ++tj)
                acc[tj] = __builtin_amdgcn_mfma_f32_32x32x16_bf16(
                    af[g & 3], bfr[tj], acc[tj], 0, 0, 0);
        }

        if (l == 0) {
            lds_barrier();   // hbuf reads of layer 0 done
            // writeback h1 (relu, bf16) into swizzled layout
#pragma unroll
            for (int q = 0; q < 4; ++q) {
                const int nb_ = n0 + 8 * q + 4 * h5;
                const int cn = nb_ >> 3, sub = nb_ & 7;
#pragma unroll
                for (int tj = 0; tj < 4; ++tj) {
                    const int j = tj * 32 + l31;
                    int addr = j * 256 + ((cn ^ l31) << 3) + sub;
                    *(uint2v*)(hbuf + addr) = (uint2v){
                        pack2(relu(acc[tj][q * 4]), relu(acc[tj][q * 4 + 1])),
                        pack2(relu(acc[tj][q * 4 + 2]), relu(acc[tj][q * 4 + 3]))};
                }
            }
            lds_barrier();
        }
    }

    // ---- pool: m2[n] = mean_j relu(acc); gather in LDS, coalesced store
#pragma unroll
    for (int r = 0; r < 16; ++r) {
        float s = relu(acc[0][r]) + relu(acc[1][r])
                + relu(acc[2][r]) + relu(acc[3][r]);
        s += __shfl_xor(s, 1);
        s += __shfl_xor(s, 2);
        s += __shfl_xor(s, 4);
        s += __shfl_xor(s, 8);
        s += __shfl_xor(s, 16);
        if (l31 == 0) {
            const int n = n0 + (r & 3) + 8 * (r >> 2) + 4 * h5;
            ms[n] = s * 0.0078125f;   // /128
        }
    }
    __syncthreads();
    if (t < 64)
        *(float4v*)(msg + w * 256 + t * 4) = *(const float4v*)(ms + t * 4);
}

// ---- decoder v2 (byte-identical to R27): out = relu(m2@W34+b34)@wd2+bd2.
//      grid 256 (every CU), 512 threads (2 waves/SIMD), 4 rows/block,
//      2-way k-split both stages, unroll 16 -> deep load pipeline.
__global__ __launch_bounds__(512) void decoder_kernel(
        const float* __restrict__ msg, const float* __restrict__ W34,
        const float* __restrict__ b34, const float* __restrict__ wd2,
        const float* __restrict__ bd2, float* __restrict__ out) {
    __shared__ float ml[4][256];        // m2 rows
    __shared__ float ps[2][4][256];     // stage1 partials [kh][r][n]
    __shared__ float tl[4][256];        // t1 rows
    __shared__ float p2[2][4][64];      // stage2 partials [kh][r][o]
    const int bx = blockIdx.x, t = threadIdx.x;
    const int r0 = bx * 4;

#pragma unroll
    for (int i = t; i < 1024; i += 512) ml[i >> 8][i & 255] = msg[r0 * 256 + i];
    __syncthreads();

    // stage 1: ps[kh][r][n] = sum_{k in kh-half} m2[r][k] * W34[k][n]
    {
        const int n = t & 255, kh = t >> 8;
        float a0 = 0.f, a1 = 0.f, a2 = 0.f, a3 = 0.f;
        const float* wp = W34 + (kh * 128) * 256 + n;
        const float* m0 = &ml[0][kh * 128];
        const float* m1 = &ml[1][kh * 128];
        const float* m2r = &ml[2][kh * 128];
        const float* m3 = &ml[3][kh * 128];
#pragma unroll 16
        for (int k = 0; k < 128; ++k) {
            const float wv_ = wp[k * 256];
            a0 += m0[k] * wv_;
            a1 += m1[k] * wv_;
            a2 += m2r[k] * wv_;
            a3 += m3[k] * wv_;
        }
        ps[kh][0][n] = a0; ps[kh][1][n] = a1; ps[kh][2][n] = a2; ps[kh][3][n] = a3;
    }
    __syncthreads();
#pragma unroll
    for (int i = t; i < 1024; i += 512) {
        const int r = i >> 8, nn = i & 255;
        tl[r][nn] = relu(ps[0][r][nn] + ps[1][r][nn] + b34[nn]);
    }
    __syncthreads();

    // stage 2: p2[kh][r][o] = sum_{k in kh-half} t1[r][k] * wd2[k][o]
    {
        const int o = t & 63, rr = (t >> 6) & 3, kh = t >> 8;
        float a = 0.f;
        const float* w2p = wd2 + (kh * 128) * 64 + o;
        const float* tp = &tl[rr][kh * 128];
#pragma unroll 16
        for (int k = 0; k < 128; ++k) a += tp[k] * w2p[k * 64];
        p2[kh][rr][o] = a;
    }
    __syncthreads();
    if (t < 256) {
        const int o = t & 63, r = t >> 6;
        out[(r0 + r) * 64 + o] = p2[0][r][o] + p2[1][r][o] + bd2[o];
    }
}

extern "C" void kernel_launch(void* const* d_in, const int* in_sizes, int n_in,
                              void* d_out, int out_size, void* d_ws, size_t ws_size,
                              hipStream_t stream) {
    const float* x0    = (const float*)d_in[0];
    const float* x1    = (const float*)d_in[1];
    const float* x2    = (const float*)d_in[2];
    const float* w_enc = (const float*)d_in[3];
    const float* b_enc = (const float*)d_in[4];
    const float* w1    = (const float*)d_in[5];
    const float* b1    = (const float*)d_in[6];
    const float* w2    = (const float*)d_in[7];
    const float* b2    = (const float*)d_in[8];
    const float* w3    = (const float*)d_in[9];
    const float* b3    = (const float*)d_in[10];
    const float* wd1   = (const float*)d_in[11];
    const float* bd1   = (const float*)d_in[12];
    const float* wd2   = (const float*)d_in[13];
    const float* bd2   = (const float*)d_in[14];
    float* out = (float*)d_out;

    // workspace: wfrag 256KB (384KB slot) | ea 1MB | eb 1MB | W34 256KB |
    //            b34 1KB | msg 1MB
    unsigned short* wt = (unsigned short*)d_ws;
    float* ea  = (float*)((char*)d_ws + 3 * 65536 * sizeof(unsigned short));
    float* eb  = ea + NROW * HID;
    float* W34 = eb + NROW * HID;
    float* b34 = W34 + 256 * 256;
    float* msg = b34 + 256;

    setup_kernel<<<785, 256, 0, stream>>>(x0, x1, x2, w_enc, b_enc, w1, w2,
                                          w3, b3, wd1, bd1, wt, ea, eb, W34, b34);
    pair_kernel<<<NROW, 512, 0, stream>>>(ea, eb, wt, b1, b2, msg);
    decoder_kernel<<<NROW / 4, 512, 0, stream>>>(msg, W34, b34, wd2, bd2, out);
}

// Round 9
// 144.983 us; speedup vs baseline: 1.1800x; 1.0155x over previous
//
#include <hip/hip_runtime.h>
#include <stdint.h>

// B=8, OBJ=128, INP=64, HID=256, D=192.
// R30 = R29 (48.1us pair, VGPR 64, no spill, 4 waves/SIMD) + VALU trim:
// 1) pack2 via v_cvt_pk_bf16_f32 (1 instr vs ~10 bit-ops; RNE identical to
//    the manual twiddle -> absmax must stay 3.814697e-06 exactly).
// 2) s_setprio(1) around the MFMA cluster (T5; 2 staggered blocks/CU give
//    the wave-role diversity it needs).
// 3) bfr ds_reads issued before af global prefetch in each k-step.
// Per-SIMD ledger at R29: 57.6k cyc/round = 16.4k MFMA + 20k VALU + 21k
// stall; pack2 is ~5k of the VALU. setup/decoder byte-identical to R27.

#define HID 256
#define NOBJ 128
#define NROW 1024   // B*OBJ

typedef __attribute__((ext_vector_type(8))) short short8;
typedef __attribute__((ext_vector_type(4))) float float4v;
typedef __attribute__((ext_vector_type(16))) float float16v;
typedef __attribute__((ext_vector_type(2))) unsigned int uint2v;

__device__ __forceinline__ unsigned int f2bf_u(float f) {
    unsigned int u = __builtin_bit_cast(unsigned int, f);
    u += 0x7fffu + ((u >> 16) & 1u);   // RNE
    return u >> 16;
}
// packed bf16 convert: dst.lo = bf16(a), dst.hi = bf16(b); RNE on gfx950.
__device__ __forceinline__ unsigned int pack2(float a, float b) {
    unsigned int r;
    asm("v_cvt_pk_bf16_f32 %0, %1, %2" : "=v"(r) : "v"(a), "v"(b));
    return r;
}
__device__ __forceinline__ float relu(float v) { return v > 0.f ? v : 0.f; }

// LDS-only barrier: leaves global-load (vmcnt) prefetches in flight.
__device__ __forceinline__ void lds_barrier() {
    asm volatile("s_waitcnt lgkmcnt(0)\n\ts_barrier" ::: "memory");
}

// ---- setup (byte-identical to R27):
//  blocks [0,16): fragment-major pack of w1,w2 (layer m = bx>>3, n-tile tau = bx&7)
//  blocks [16,528): encoder, 2 rows each (fold b_enc into ea)
//  blocks [528,784): W34 row m = bx-528:  W34[m][o] = sum_k w3[m][k]*wd1[k][o]
//  block  784:       b34[o] = sum_k b3[k]*wd1[k][o] + bd1[o]
__global__ void setup_kernel(const float* __restrict__ x0, const float* __restrict__ x1,
                             const float* __restrict__ x2, const float* __restrict__ w_enc,
                             const float* __restrict__ b_enc,
                             const float* __restrict__ w1, const float* __restrict__ w2,
                             const float* __restrict__ w3, const float* __restrict__ b3,
                             const float* __restrict__ wd1, const float* __restrict__ bd1,
                             unsigned short* __restrict__ wt,
                             float* __restrict__ ea, float* __restrict__ eb,
                             float* __restrict__ W34, float* __restrict__ b34) {
    const int bx = blockIdx.x, t = threadIdx.x;
    __shared__ float lw[256][33];          // [k][n-within-tile]
    __shared__ float xs[2][192];
    if (bx < 16) {
        const int m = bx >> 3, tau = bx & 7;
        const float* w = (m == 0) ? w1 : w2;
        const int n = t & 31, kk = t >> 5;     // 8 k-rows per pass
#pragma unroll
        for (int rep = 0; rep < 32; ++rep) {
            int k = rep * 8 + kk;
            lw[k][n] = w[k * 256 + tau * 32 + n];   // coalesced 128B segments
        }
        __syncthreads();
        unsigned short* outp = wt + (m * 8 + tau) * 8192;
        const int lane = t & 63, wq = t >> 6;
        const int h5 = lane >> 5, l31n = lane & 31;
#pragma unroll
        for (int rep = 0; rep < 4; ++rep) {
            const int kb = wq * 4 + rep;
            short8 v;
#pragma unroll
            for (int e = 0; e < 8; ++e)
                v[e] = (short)f2bf_u(lw[kb * 16 + h5 * 8 + e][l31n]);
            *(short8*)(outp + kb * 512 + lane * 8) = v;   // wave-contiguous 1KB
        }
        return;
    }
    if (bx < 528) {
        const int e = bx - 16;                 // 512 groups x 2 rows
        for (int idx = t; idx < 384; idx += 256) {
            int r = idx / 192, d = idx % 192;
            int row = e * 2 + r;
            float v = (d < 64) ? x0[row * 64 + d]
                    : (d < 128) ? x1[row * 64 + d - 64]
                    : x2[row * 64 + d - 128];
            xs[r][d] = v;
        }
        __syncthreads();
        float aA[2] = {0.f, 0.f}, aB[2] = {0.f, 0.f};
#pragma unroll 16
        for (int d = 0; d < 192; ++d) {
            float wa = w_enc[d * 256 + t];
            float wb = w_enc[(192 + d) * 256 + t];
#pragma unroll
            for (int r = 0; r < 2; ++r) { aA[r] += xs[r][d] * wa; aB[r] += xs[r][d] * wb; }
        }
        float be = b_enc[t];
#pragma unroll
        for (int r = 0; r < 2; ++r) {
            ea[(e * 2 + r) * 256 + t] = aA[r] + be;
            eb[(e * 2 + r) * 256 + t] = aB[r];
        }
        return;
    }
    if (bx < 784) {
        const int m = bx - 528;
        float a = 0.f;
#pragma unroll 8
        for (int k = 0; k < 256; ++k) a += w3[m * 256 + k] * wd1[k * 256 + t];
        W34[m * 256 + t] = a;
        return;
    }
    {   // b34
        float a = bd1[t];
#pragma unroll 8
        for (int k = 0; k < 256; ++k) a += b3[k] * wd1[k * 256 + t];
        b34[t] = a;
    }
}

// ---- pair MLP (2 layers) + pool: grid 1024, one WG (512 thr, 8 waves) per
//      (b,i). Full 128 j-rows in 64KB LDS; swizzle: elem(j,k) at
//      j*256 + ((k>>3 ^ (j&31))<<3) + (k&7). Wave wv owns n-slice n0=wv*32
//      as tj=4 tiles of 32x32x16 (4 MFMA/k-step). af ring-4, bfr single-buf.
__global__ __launch_bounds__(512, 4) void pair_kernel(
        const float* __restrict__ ea, const float* __restrict__ eb,
        const unsigned short* __restrict__ wt,
        const float* __restrict__ b1, const float* __restrict__ b2,
        float* __restrict__ msg) {
    __shared__ __align__(16) unsigned short hbuf[128 * 256];   // 64 KB
    __shared__ float ms[HID];

    const int w = blockIdx.x, b = w >> 7;
    const int t = threadIdx.x, wv = t >> 6, lane = t & 63;
    const int l31 = lane & 31, h5 = lane >> 5;
    const int n0 = wv * 32;

    const unsigned short* aptr = wt + lane * 8;   // + ((l*8 + wv)*16 + kb)*512

    short8 af[4], bfr[4];
    // ring-4 preload: steps g = 0,1,2 of layer 0
#pragma unroll
    for (int pg = 0; pg < 3; ++pg)
        af[pg] = *(const short8*)(aptr + (wv * 16 + pg) * 512);

    // preamble: h0[j][k] = relu(ea[w][k] + eb[b*128+j][k]); wave fills 16 rows
    {
        const float4v va = *(const float4v*)(ea + w * 256 + lane * 4);
        const float* ebbase = eb + (b * NOBJ) * 256;
        const int c = lane >> 1, sub = (lane & 1) * 4;
#pragma unroll 4
        for (int jj = 0; jj < 16; ++jj) {
            const int j = wv * 16 + jj;
            float4v vb = *(const float4v*)(ebbase + j * 256 + lane * 4);
            int addr = j * 256 + ((c ^ (j & 31)) << 3) + sub;
            *(uint2v*)(hbuf + addr) = (uint2v){
                pack2(relu(va[0] + vb[0]), relu(va[1] + vb[1])),
                pack2(relu(va[2] + vb[2]), relu(va[3] + vb[3]))};
        }
    }
    lds_barrier();

    int jb[4];
#pragma unroll
    for (int tj = 0; tj < 4; ++tj) jb[tj] = (tj * 32 + l31) * 256;

    float16v acc[4];   // [tj]

#pragma unroll
    for (int l = 0; l < 2; ++l) {
        const float* bias = (l == 0) ? b1 : b2;
#pragma unroll
        for (int q = 0; q < 4; ++q) {
            float4v bv = *(const float4v*)(bias + n0 + q * 8 + h5 * 4);
#pragma unroll
            for (int i = 0; i < 4; ++i)
#pragma unroll
                for (int tj = 0; tj < 4; ++tj)
                    acc[tj][q * 4 + i] = bv[i];
        }
#pragma unroll
        for (int kb = 0; kb < 16; ++kb) {
            const int g = l * 16 + kb, gp = g + 3;
            // bfr ds_reads first: the MFMA cluster depends on these
            {
                const int off = (((kb * 2 + h5) ^ l31) << 3);
#pragma unroll
                for (int tj = 0; tj < 4; ++tj)
                    bfr[tj] = *(const short8*)(hbuf + jb[tj] + off);
            }
            if (gp < 32) {   // ring-4: prefetch 3 steps ahead (crosses layers)
                const int lp = gp >> 4, kp = gp & 15;
                af[gp & 3] = *(const short8*)(aptr + ((lp * 8 + wv) * 16 + kp) * 512);
            }
            __builtin_amdgcn_s_setprio(1);
#pragma unroll
            for (int tj = 0; tj < 4; ++tj)
                acc[tj] = __builtin_amdgcn_mfma_f32_32x32x16_bf16(
                    af[g & 3], bfr[tj], acc[tj], 0, 0, 0);
            __builtin_amdgcn_s_setprio(0);
        }

        if (l == 0) {
            lds_barrier();   // hbuf reads of layer 0 done
            // writeback h1 (relu, bf16) into swizzled layout
#pragma unroll
            for (int q = 0; q < 4; ++q) {
                const int nb_ = n0 + 8 * q + 4 * h5;
                const int cn = nb_ >> 3, sub = nb_ & 7;
#pragma unroll
                for (int tj = 0; tj < 4; ++tj) {
                    const int j = tj * 32 + l31;
                    int addr = j * 256 + ((cn ^ l31) << 3) + sub;
                    *(uint2v*)(hbuf + addr) = (uint2v){
                        pack2(relu(acc[tj][q * 4]), relu(acc[tj][q * 4 + 1])),
                        pack2(relu(acc[tj][q * 4 + 2]), relu(acc[tj][q * 4 + 3]))};
                }
            }
            lds_barrier();
        }
    }

    // ---- pool: m2[n] = mean_j relu(acc); gather in LDS, coalesced store
#pragma unroll
    for (int r = 0; r < 16; ++r) {
        float s = relu(acc[0][r]) + relu(acc[1][r])
                + relu(acc[2][r]) + relu(acc[3][r]);
        s += __shfl_xor(s, 1);
        s += __shfl_xor(s, 2);
        s += __shfl_xor(s, 4);
        s += __shfl_xor(s, 8);
        s += __shfl_xor(s, 16);
        if (l31 == 0) {
            const int n = n0 + (r & 3) + 8 * (r >> 2) + 4 * h5;
            ms[n] = s * 0.0078125f;   // /128
        }
    }
    __syncthreads();
    if (t < 64)
        *(float4v*)(msg + w * 256 + t * 4) = *(const float4v*)(ms + t * 4);
}

// ---- decoder v2 (byte-identical to R27): out = relu(m2@W34+b34)@wd2+bd2.
//      grid 256 (every CU), 512 threads (2 waves/SIMD), 4 rows/block,
//      2-way k-split both stages, unroll 16 -> deep load pipeline.
__global__ __launch_bounds__(512) void decoder_kernel(
        const float* __restrict__ msg, const float* __restrict__ W34,
        const float* __restrict__ b34, const float* __restrict__ wd2,
        const float* __restrict__ bd2, float* __restrict__ out) {
    __shared__ float ml[4][256];        // m2 rows
    __shared__ float ps[2][4][256];     // stage1 partials [kh][r][n]
    __shared__ float tl[4][256];        // t1 rows
    __shared__ float p2[2][4][64];      // stage2 partials [kh][r][o]
    const int bx = blockIdx.x, t = threadIdx.x;
    const int r0 = bx * 4;

#pragma unroll
    for (int i = t; i < 1024; i += 512) ml[i >> 8][i & 255] = msg[r0 * 256 + i];
    __syncthreads();

    // stage 1: ps[kh][r][n] = sum_{k in kh-half} m2[r][k] * W34[k][n]
    {
        const int n = t & 255, kh = t >> 8;
        float a0 = 0.f, a1 = 0.f, a2 = 0.f, a3 = 0.f;
        const float* wp = W34 + (kh * 128) * 256 + n;
        const float* m0 = &ml[0][kh * 128];
        const float* m1 = &ml[1][kh * 128];
        const float* m2r = &ml[2][kh * 128];
        const float* m3 = &ml[3][kh * 128];
#pragma unroll 16
        for (int k = 0; k < 128; ++k) {
            const float wv_ = wp[k * 256];
            a0 += m0[k] * wv_;
            a1 += m1[k] * wv_;
            a2 += m2r[k] * wv_;
            a3 += m3[k] * wv_;
        }
        ps[kh][0][n] = a0; ps[kh][1][n] = a1; ps[kh][2][n] = a2; ps[kh][3][n] = a3;
    }
    __syncthreads();
#pragma unroll
    for (int i = t; i < 1024; i += 512) {
        const int r = i >> 8, nn = i & 255;
        tl[r][nn] = relu(ps[0][r][nn] + ps[1][r][nn] + b34[nn]);
    }
    __syncthreads();

    // stage 2: p2[kh][r][o] = sum_{k in kh-half} t1[r][k] * wd2[k][o]
    {
        const int o = t & 63, rr = (t >> 6) & 3, kh = t >> 8;
        float a = 0.f;
        const float* w2p = wd2 + (kh * 128) * 64 + o;
        const float* tp = &tl[rr][kh * 128];
#pragma unroll 16
        for (int k = 0; k < 128; ++k) a += tp[k] * w2p[k * 64];
        p2[kh][rr][o] = a;
    }
    __syncthreads();
    if (t < 256) {
        const int o = t & 63, r = t >> 6;
        out[(r0 + r) * 64 + o] = p2[0][r][o] + p2[1][r][o] + bd2[o];
    }
}

extern "C" void kernel_launch(void* const* d_in, const int* in_sizes, int n_in,
                              void* d_out, int out_size, void* d_ws, size_t ws_size,
                              hipStream_t stream) {
    const float* x0    = (const float*)d_in[0];
    const float* x1    = (const float*)d_in[1];
    const float* x2    = (const float*)d_in[2];
    const float* w_enc = (const float*)d_in[3];
    const float* b_enc = (const float*)d_in[4];
    const float* w1    = (const float*)d_in[5];
    const float* b1    = (const float*)d_in[6];
    const float* w2    = (const float*)d_in[7];
    const float* b2    = (const float*)d_in[8];
    const float* w3    = (const float*)d_in[9];
    const float* b3    = (const float*)d_in[10];
    const float* wd1   = (const float*)d_in[11];
    const float* bd1   = (const float*)d_in[12];
    const float* wd2   = (const float*)d_in[13];
    const float* bd2   = (const float*)d_in[14];
    float* out = (float*)d_out;

    // workspace: wfrag 256KB (384KB slot) | ea 1MB | eb 1MB | W34 256KB |
    //            b34 1KB | msg 1MB
    unsigned short* wt = (unsigned short*)d_ws;
    float* ea  = (float*)((char*)d_ws + 3 * 65536 * sizeof(unsigned short));
    float* eb  = ea + NROW * HID;
    float* W34 = eb + NROW * HID;
    float* b34 = W34 + 256 * 256;
    float* msg = b34 + 256;

    setup_kernel<<<785, 256, 0, stream>>>(x0, x1, x2, w_enc, b_enc, w1, w2,
                                          w3, b3, wd1, bd1, wt, ea, eb, W34, b34);
    pair_kernel<<<NROW, 512, 0, stream>>>(ea, eb, wt, b1, b2, msg);
    decoder_kernel<<<NROW / 4, 512, 0, stream>>>(msg, W34, b34, wd2, bd2, out);
}